// Round 1
// baseline (150.765 us; speedup 1.0000x reference)
//
#include <hip/hip_runtime.h>
#include <hip/hip_fp16.h>
#include <cstdint>

namespace {

constexpr int BATCH   = 8192;
constexpr int IN      = 64;
constexpr int U       = 128;
constexpr int TB      = 8;      // batches per block
constexpr int NT      = 1024;   // threads per block (16 waves)
constexpr int UNFOLDS = 3;
constexpr float LOG2E = 1.4426950408889634f;

union HalfPack { uint32_t u; __half2 h2; };

__device__ __forceinline__ uint32_t pack2(float lo, float hi) {
  __half l = __float2half_rn(lo);
  __half h = __float2half_rn(hi);
  return (uint32_t)__half_as_ushort(l) | ((uint32_t)__half_as_ushort(h) << 16);
}

__global__ __launch_bounds__(NT)
void ltc_fused(const float* __restrict__ inputs, const float* __restrict__ state,
               const float* __restrict__ s_mu, const float* __restrict__ s_sigma,
               const float* __restrict__ s_W, const float* __restrict__ s_erev,
               const float* __restrict__ r_mu, const float* __restrict__ r_sigma,
               const float* __restrict__ r_W, const float* __restrict__ r_erev,
               const float* __restrict__ vleak, const float* __restrict__ gleak,
               const float* __restrict__ cm_t, float* __restrict__ out)
{
  // 128 KiB weight pack (recurrent); first 64 KiB reused for sensory in phase 1.
  __shared__ uint2 pack_s[U * U];
  __shared__ float vp_s[2][TB][U];   // ping-pong v_pre exchange
  __shared__ float inp_s[TB * IN];   // input tile

  const int tid = threadIdx.x;
  const int u   = tid & (U - 1);
  const int bl  = tid >> 7;            // 0..TB-1
  const int b0  = blockIdx.x * TB;
  const int b   = b0 + bl;

  // per-u constants (L2 broadcast)
  const float cm   = cm_t[u];
  const float gl   = gleak[u];
  const float numc = gl * vleak[u];
  const float denc = cm + gl + 1e-8f;

  // ---- phase 1: stage sensory packs {A|B, W|We} as f16x2 ----
  for (int k = tid; k < IN * U; k += NT) {
    const float sg = s_sigma[k];
    const float w  = s_W[k];
    uint2 p;
    p.x = pack2(-LOG2E * sg, LOG2E * sg * s_mu[k]);
    p.y = pack2(w, w * s_erev[k]);
    pack_s[k] = p;
  }
  for (int k = tid; k < TB * IN; k += NT) inp_s[k] = inputs[b0 * IN + k];
  float v_own = state[b * U + u];
  vp_s[0][bl][u] = v_own;
  __syncthreads();

  // ---- sensory reduction over IN ----
  float num_s = 0.f, den_s = 0.f;
#pragma unroll 8
  for (int i = 0; i < IN; ++i) {
    const float v = inp_s[bl * IN + i];           // wave-broadcast
    const uint2 p = pack_s[i * U + u];            // contiguous b64 per wave
    HalfPack ab; ab.u = p.x;
    HalfPack ww; ww.u = p.y;
    const float x2 = fmaf(__low2float(ab.h2), v, __high2float(ab.h2)); // -log2e*sigma*(v-mu)
    const float e  = __builtin_amdgcn_exp2f(x2);
    const float r  = __builtin_amdgcn_rcpf(1.0f + e);                  // sigmoid
    den_s = fmaf(__low2float(ww.h2),  r, den_s);
    num_s = fmaf(__high2float(ww.h2), r, num_s);
  }
  __syncthreads();  // everyone done reading sensory region

  // ---- phase 2: stage recurrent packs (overwrites sensory region) ----
  for (int k = tid; k < U * U; k += NT) {
    const float sg = r_sigma[k];
    const float w  = r_W[k];
    uint2 p;
    p.x = pack2(-LOG2E * sg, LOG2E * sg * r_mu[k]);
    p.y = pack2(w, w * r_erev[k]);
    pack_s[k] = p;
  }
  __syncthreads();

  // ---- 3 unfolds, v_pre via ping-pong LDS ----
  int cur = 0;
#pragma unroll
  for (int t = 0; t < UNFOLDS; ++t) {
    float num = num_s, den = den_s;
#pragma unroll 8
    for (int i = 0; i < U; ++i) {
      const float v = vp_s[cur][bl][i];           // wave-broadcast
      const uint2 p = pack_s[i * U + u];
      HalfPack ab; ab.u = p.x;
      HalfPack ww; ww.u = p.y;
      const float x2 = fmaf(__low2float(ab.h2), v, __high2float(ab.h2));
      const float e  = __builtin_amdgcn_exp2f(x2);
      const float r  = __builtin_amdgcn_rcpf(1.0f + e);
      den = fmaf(__low2float(ww.h2),  r, den);
      num = fmaf(__high2float(ww.h2), r, num);
    }
    const float vnew = (fmaf(cm, v_own, numc) + num) * __builtin_amdgcn_rcpf(denc + den);
    v_own = vnew;
    if (t == UNFOLDS - 1) {
      out[b * U + u] = vnew;
    } else {
      vp_s[cur ^ 1][bl][u] = vnew;
      __syncthreads();
      cur ^= 1;
    }
  }
}

} // namespace

extern "C" void kernel_launch(void* const* d_in, const int* in_sizes, int n_in,
                              void* d_out, int out_size, void* d_ws, size_t ws_size,
                              hipStream_t stream) {
  const float* inputs   = (const float*)d_in[0];
  const float* state    = (const float*)d_in[1];
  const float* s_mu     = (const float*)d_in[2];
  const float* s_sigma  = (const float*)d_in[3];
  const float* s_W      = (const float*)d_in[4];
  const float* s_erev   = (const float*)d_in[5];
  const float* r_mu     = (const float*)d_in[6];
  const float* r_sigma  = (const float*)d_in[7];
  const float* r_W      = (const float*)d_in[8];
  const float* r_erev   = (const float*)d_in[9];
  const float* vleak    = (const float*)d_in[10];
  const float* gleak    = (const float*)d_in[11];
  const float* cm_t     = (const float*)d_in[12];
  float* out = (float*)d_out;

  ltc_fused<<<dim3(BATCH / TB), dim3(NT), 0, stream>>>(
      inputs, state, s_mu, s_sigma, s_W, s_erev,
      r_mu, r_sigma, r_W, r_erev, vleak, gleak, cm_t, out);
}

// Round 3
// 115.224 us; speedup vs baseline: 1.3085x; 1.3085x over previous
//
#include <hip/hip_runtime.h>
#include <hip/hip_fp16.h>
#include <cstdint>

namespace {

constexpr int BATCH   = 8192;
constexpr int IN      = 64;
constexpr int U       = 128;
constexpr int R       = 4;        // batches per thread
constexpr int TB      = 32;       // batches per block (8 thread-groups * R)
constexpr int NT      = 1024;     // threads per block (16 waves)
constexpr int UNFOLDS = 3;
constexpr int PAD     = 36;       // floats per LDS row (16B-aligned, bank-spread)
constexpr float LOG2E = 1.4426950408889634f;

union HP { uint32_t u; __half2 h2; };

__device__ __forceinline__ uint32_t pack2(float lo, float hi) {
  __half l = __float2half_rn(lo);
  __half h = __float2half_rn(hi);
  return (uint32_t)__half_as_ushort(l) | ((uint32_t)__half_as_ushort(h) << 16);
}

__global__ __launch_bounds__(NT, 4)
void ltc_fused(const float* __restrict__ inputs, const float* __restrict__ state,
               const float* __restrict__ s_mu, const float* __restrict__ s_sigma,
               const float* __restrict__ s_W, const float* __restrict__ s_erev,
               const float* __restrict__ r_mu, const float* __restrict__ r_sigma,
               const float* __restrict__ r_W, const float* __restrict__ r_erev,
               const float* __restrict__ vleak, const float* __restrict__ gleak,
               const float* __restrict__ cm_t, float* __restrict__ out)
{
  __shared__ uint2 pack_s[U * U];       // 128 KB: recurrent packs (sensory reuses first 64 KB)
  __shared__ float vp_s[U][PAD];        // 18 KB: v_pre, [presyn i][b_local]
  __shared__ float inp_s[IN][PAD];      // 9 KB: inputs, [i][b_local]

  const int tid = threadIdx.x;
  const int u   = tid & (U - 1);
  const int bl  = tid >> 7;             // 0..7
  const int b0  = blockIdx.x * TB;

  // per-u constants
  const float cm   = cm_t[u];
  const float gl   = gleak[u];
  const float numc = gl * vleak[u];
  const float denc = cm + gl + 1e-8f;

  // ---- stage sensory packs {A|B, W|We} ----
  for (int k = tid; k < IN * U; k += NT) {
    const float sg = s_sigma[k];
    const float w  = s_W[k];
    uint2 p;
    p.x = pack2(-LOG2E * sg, LOG2E * sg * s_mu[k]);
    p.y = pack2(w, w * s_erev[k]);
    pack_s[k] = p;
  }
  // ---- stage inputs transposed: inp_s[i][b_local] ----
  for (int k = tid; k < TB * IN; k += NT) {
    const int bloc = k >> 6;            // k / IN
    const int i    = k & (IN - 1);
    inp_s[i][bloc] = inputs[b0 * IN + k];
  }
  // ---- stage state transposed: vp_s[i][b_local] ----
  for (int k = tid; k < TB * U; k += NT) {
    const int bloc = k >> 7;            // k / U
    const int i    = k & (U - 1);
    vp_s[i][bloc] = state[b0 * U + k];
  }
  // own v_pre (coalesced global, L2-hot)
  float vo[R];
#pragma unroll
  for (int r = 0; r < R; ++r) vo[r] = state[(b0 + bl * R + r) * U + u];
  __syncthreads();

  // ---- sensory reduction over IN, R batches per thread ----
  float num_s[R], den_s[R];
#pragma unroll
  for (int r = 0; r < R; ++r) { num_s[r] = 0.f; den_s[r] = 0.f; }
#pragma unroll 2
  for (int i = 0; i < IN; ++i) {
    const float4 v4 = *reinterpret_cast<const float4*>(&inp_s[i][bl * R]); // broadcast
    const uint2 p = pack_s[i * U + u];
    HP ab; ab.u = p.x;
    HP ww; ww.u = p.y;
    const float A  = __low2float(ab.h2);
    const float Bb = __high2float(ab.h2);
    const float W  = __low2float(ww.h2);
    const float We = __high2float(ww.h2);
#pragma unroll
    for (int r = 0; r < R; ++r) {
      const float x2 = fmaf(A, (&v4.x)[r], Bb);     // -log2e*sigma*(v-mu)
      const float e  = __builtin_amdgcn_exp2f(x2);
      const float rc = __builtin_amdgcn_rcpf(1.0f + e);
      den_s[r] = fmaf(W,  rc, den_s[r]);
      num_s[r] = fmaf(We, rc, num_s[r]);
    }
  }
  __syncthreads();  // sensory region reads done

  // ---- stage recurrent packs (overwrites sensory region) ----
  for (int k = tid; k < U * U; k += NT) {
    const float sg = r_sigma[k];
    const float w  = r_W[k];
    uint2 p;
    p.x = pack2(-LOG2E * sg, LOG2E * sg * r_mu[k]);
    p.y = pack2(w, w * r_erev[k]);
    pack_s[k] = p;
  }
  __syncthreads();

  // ---- 3 unfolds, single vp buffer ----
#pragma unroll
  for (int t = 0; t < UNFOLDS; ++t) {
    float num[R], den[R];
#pragma unroll
    for (int r = 0; r < R; ++r) { num[r] = num_s[r]; den[r] = den_s[r]; }
#pragma unroll 2
    for (int i = 0; i < U; ++i) {
      const float4 v4 = *reinterpret_cast<const float4*>(&vp_s[i][bl * R]); // broadcast
      const uint2 p = pack_s[i * U + u];
      HP ab; ab.u = p.x;
      HP ww; ww.u = p.y;
      const float A  = __low2float(ab.h2);
      const float Bb = __high2float(ab.h2);
      const float W  = __low2float(ww.h2);
      const float We = __high2float(ww.h2);
#pragma unroll
      for (int r = 0; r < R; ++r) {
        const float x2 = fmaf(A, (&v4.x)[r], Bb);
        const float e  = __builtin_amdgcn_exp2f(x2);
        const float rc = __builtin_amdgcn_rcpf(1.0f + e);
        den[r] = fmaf(W,  rc, den[r]);
        num[r] = fmaf(We, rc, num[r]);
      }
    }
    float vnew[R];
#pragma unroll
    for (int r = 0; r < R; ++r) {
      vnew[r] = (fmaf(cm, vo[r], numc) + num[r]) * __builtin_amdgcn_rcpf(denc + den[r]);
      vo[r] = vnew[r];
    }
    if (t == UNFOLDS - 1) {
#pragma unroll
      for (int r = 0; r < R; ++r) out[(b0 + bl * R + r) * U + u] = vnew[r];
    } else {
      __syncthreads();  // all reads of vp_s done
      *reinterpret_cast<float4*>(&vp_s[u][bl * R]) =
          make_float4(vnew[0], vnew[1], vnew[2], vnew[3]);
      __syncthreads();
    }
  }
}

} // namespace

extern "C" void kernel_launch(void* const* d_in, const int* in_sizes, int n_in,
                              void* d_out, int out_size, void* d_ws, size_t ws_size,
                              hipStream_t stream) {
  const float* inputs   = (const float*)d_in[0];
  const float* state    = (const float*)d_in[1];
  const float* s_mu     = (const float*)d_in[2];
  const float* s_sigma  = (const float*)d_in[3];
  const float* s_W      = (const float*)d_in[4];
  const float* s_erev   = (const float*)d_in[5];
  const float* r_mu     = (const float*)d_in[6];
  const float* r_sigma  = (const float*)d_in[7];
  const float* r_W      = (const float*)d_in[8];
  const float* r_erev   = (const float*)d_in[9];
  const float* vleak    = (const float*)d_in[10];
  const float* gleak    = (const float*)d_in[11];
  const float* cm_t     = (const float*)d_in[12];
  float* out = (float*)d_out;

  ltc_fused<<<dim3(BATCH / TB), dim3(NT), 0, stream>>>(
      inputs, state, s_mu, s_sigma, s_W, s_erev,
      r_mu, r_sigma, r_W, r_erev, vleak, gleak, cm_t, out);
}

// Round 5
// 112.183 us; speedup vs baseline: 1.3439x; 1.0271x over previous
//
#include <hip/hip_runtime.h>
#include <hip/hip_fp16.h>
#include <cstdint>

namespace {

typedef _Float16 h2 __attribute__((ext_vector_type(2)));

constexpr int BATCH   = 8192;
constexpr int IN      = 64;
constexpr int U       = 128;
constexpr int R       = 4;        // batches per thread
constexpr int TB      = 32;       // batches per block
constexpr int NT      = 1024;     // threads per block (16 waves)
constexpr int UNFOLDS = 3;
constexpr int PAD     = 36;       // floats per LDS row
constexpr float LOG2E = 1.4426950408889634f;

union HU { uint32_t u; h2 h; };

__device__ __forceinline__ uint32_t pack2(float lo, float hi) {
  __half l = __float2half_rn(lo);
  __half h = __float2half_rn(hi);
  return (uint32_t)__half_as_ushort(l) | ((uint32_t)__half_as_ushort(h) << 16);
}

// Gate pair: weights for i-pair packed as {A0|B0},{A1|B1} (f16, pre-converted
// to f32 by caller, amortized over R) and {W0|W1},{We0|We1} (h2, consumed by
// dot2). Sigmoids packed to f16x2 once, both accumulators via v_dot2_f32_f16.
__device__ __forceinline__ void gate2(float A0, float B0, float A1, float B1,
                                      h2 wpk, h2 wepk, float v0, float v1,
                                      float& num, float& den) {
  const float t0 = fmaf(A0, v0, B0);              // -log2e*sigma*(v-mu)
  const float t1 = fmaf(A1, v1, B1);
  const float e0 = __builtin_amdgcn_exp2f(t0);
  const float e1 = __builtin_amdgcn_exp2f(t1);
  const float rc0 = __builtin_amdgcn_rcpf(1.0f + e0);   // sigmoid
  const float rc1 = __builtin_amdgcn_rcpf(1.0f + e1);
  const h2 rpk = __builtin_bit_cast(h2, __builtin_amdgcn_cvt_pkrtz(rc0, rc1));
  den = __builtin_amdgcn_fdot2(rpk, wpk,  den, false);  // += W0*rc0 + W1*rc1
  num = __builtin_amdgcn_fdot2(rpk, wepk, num, false);  // += We0*rc0 + We1*rc1
}

__global__ __launch_bounds__(NT, 4)
void ltc_fused(const float* __restrict__ inputs, const float* __restrict__ state,
               const float* __restrict__ s_mu, const float* __restrict__ s_sigma,
               const float* __restrict__ s_W, const float* __restrict__ s_erev,
               const float* __restrict__ r_mu, const float* __restrict__ r_sigma,
               const float* __restrict__ r_W, const float* __restrict__ r_erev,
               const float* __restrict__ vleak, const float* __restrict__ gleak,
               const float* __restrict__ cm_t, float* __restrict__ out)
{
  // 128 KB: recurrent i-pair packs {AB0, AB1, Wpk, Wepk}; sensory reuses 64 KB.
  __shared__ uint4 pack_s[(U / 2) * U];
  __shared__ float vp_s[U][PAD];        // v_pre, [presyn i][b_local]
  __shared__ float inp_s[IN][PAD];      // inputs, [i][b_local]

  const int tid = threadIdx.x;
  const int u   = tid & (U - 1);
  const int bl  = tid >> 7;             // 0..7
  const int b0  = blockIdx.x * TB;

  // per-u constants
  const float cm   = cm_t[u];
  const float gl   = gleak[u];
  const float numc = gl * vleak[u];
  const float denc = cm + gl + 1e-8f;

  // ---- stage sensory packs (i-pair interleaved) ----
  for (int k = tid; k < (IN / 2) * U; k += NT) {
    const int p  = k >> 7;              // pair index
    const int uu = k & (U - 1);
    const int i0 = 2 * p, i1 = i0 + 1;
    const float sg0 = s_sigma[i0 * U + uu], sg1 = s_sigma[i1 * U + uu];
    const float w0  = s_W[i0 * U + uu],     w1  = s_W[i1 * U + uu];
    uint4 q;
    q.x = pack2(-LOG2E * sg0, LOG2E * sg0 * s_mu[i0 * U + uu]);
    q.y = pack2(-LOG2E * sg1, LOG2E * sg1 * s_mu[i1 * U + uu]);
    q.z = pack2(w0, w1);
    q.w = pack2(w0 * s_erev[i0 * U + uu], w1 * s_erev[i1 * U + uu]);
    pack_s[k] = q;
  }
  // ---- stage inputs transposed: inp_s[i][b_local] ----
  for (int k = tid; k < TB * IN; k += NT) {
    const int bloc = k >> 6;
    const int i    = k & (IN - 1);
    inp_s[i][bloc] = inputs[b0 * IN + k];
  }
  // ---- stage state transposed: vp_s[i][b_local] ----
  for (int k = tid; k < TB * U; k += NT) {
    const int bloc = k >> 7;
    const int i    = k & (U - 1);
    vp_s[i][bloc] = state[b0 * U + k];
  }
  float vo[R];
#pragma unroll
  for (int r = 0; r < R; ++r) vo[r] = state[(b0 + bl * R + r) * U + u];
  __syncthreads();

  // ---- sensory reduction over IN (32 pairs) ----
  float num_s[R], den_s[R];
#pragma unroll
  for (int r = 0; r < R; ++r) { num_s[r] = 0.f; den_s[r] = 0.f; }
#pragma unroll 2
  for (int p = 0; p < IN / 2; ++p) {
    const uint4 q = pack_s[p * U + u];
    const float4 va = *reinterpret_cast<const float4*>(&inp_s[2 * p][bl * R]);
    const float4 vb = *reinterpret_cast<const float4*>(&inp_s[2 * p + 1][bl * R]);
    HU x, y, z, w; x.u = q.x; y.u = q.y; z.u = q.z; w.u = q.w;
    const float A0 = (float)x.h.x, B0 = (float)x.h.y;
    const float A1 = (float)y.h.x, B1 = (float)y.h.y;
#pragma unroll
    for (int r = 0; r < R; ++r)
      gate2(A0, B0, A1, B1, z.h, w.h, (&va.x)[r], (&vb.x)[r], num_s[r], den_s[r]);
  }
  __syncthreads();  // sensory region reads done

  // ---- stage recurrent packs (overwrites sensory region) ----
  for (int k = tid; k < (U / 2) * U; k += NT) {
    const int p  = k >> 7;
    const int uu = k & (U - 1);
    const int i0 = 2 * p, i1 = i0 + 1;
    const float sg0 = r_sigma[i0 * U + uu], sg1 = r_sigma[i1 * U + uu];
    const float w0  = r_W[i0 * U + uu],     w1  = r_W[i1 * U + uu];
    uint4 q;
    q.x = pack2(-LOG2E * sg0, LOG2E * sg0 * r_mu[i0 * U + uu]);
    q.y = pack2(-LOG2E * sg1, LOG2E * sg1 * r_mu[i1 * U + uu]);
    q.z = pack2(w0, w1);
    q.w = pack2(w0 * r_erev[i0 * U + uu], w1 * r_erev[i1 * U + uu]);
    pack_s[k] = q;
  }
  __syncthreads();

  // ---- 3 unfolds (64 pairs each) ----
#pragma unroll
  for (int t = 0; t < UNFOLDS; ++t) {
    float num[R], den[R];
#pragma unroll
    for (int r = 0; r < R; ++r) { num[r] = num_s[r]; den[r] = den_s[r]; }
#pragma unroll 2
    for (int p = 0; p < U / 2; ++p) {
      const uint4 q = pack_s[p * U + u];
      const float4 va = *reinterpret_cast<const float4*>(&vp_s[2 * p][bl * R]);
      const float4 vb = *reinterpret_cast<const float4*>(&vp_s[2 * p + 1][bl * R]);
      HU x, y, z, w; x.u = q.x; y.u = q.y; z.u = q.z; w.u = q.w;
      const float A0 = (float)x.h.x, B0 = (float)x.h.y;
      const float A1 = (float)y.h.x, B1 = (float)y.h.y;
#pragma unroll
      for (int r = 0; r < R; ++r)
        gate2(A0, B0, A1, B1, z.h, w.h, (&va.x)[r], (&vb.x)[r], num[r], den[r]);
    }
    float vnew[R];
#pragma unroll
    for (int r = 0; r < R; ++r) {
      vnew[r] = (fmaf(cm, vo[r], numc) + num[r]) * __builtin_amdgcn_rcpf(denc + den[r]);
      vo[r] = vnew[r];
    }
    if (t == UNFOLDS - 1) {
#pragma unroll
      for (int r = 0; r < R; ++r) out[(b0 + bl * R + r) * U + u] = vnew[r];
    } else {
      __syncthreads();  // all reads of vp_s done
      *reinterpret_cast<float4*>(&vp_s[u][bl * R]) =
          make_float4(vnew[0], vnew[1], vnew[2], vnew[3]);
      __syncthreads();
    }
  }
}

} // namespace

extern "C" void kernel_launch(void* const* d_in, const int* in_sizes, int n_in,
                              void* d_out, int out_size, void* d_ws, size_t ws_size,
                              hipStream_t stream) {
  const float* inputs   = (const float*)d_in[0];
  const float* state    = (const float*)d_in[1];
  const float* s_mu     = (const float*)d_in[2];
  const float* s_sigma  = (const float*)d_in[3];
  const float* s_W      = (const float*)d_in[4];
  const float* s_erev   = (const float*)d_in[5];
  const float* r_mu     = (const float*)d_in[6];
  const float* r_sigma  = (const float*)d_in[7];
  const float* r_W      = (const float*)d_in[8];
  const float* r_erev   = (const float*)d_in[9];
  const float* vleak    = (const float*)d_in[10];
  const float* gleak    = (const float*)d_in[11];
  const float* cm_t     = (const float*)d_in[12];
  float* out = (float*)d_out;

  ltc_fused<<<dim3(BATCH / TB), dim3(NT), 0, stream>>>(
      inputs, state, s_mu, s_sigma, s_W, s_erev,
      r_mu, r_sigma, r_W, r_erev, vleak, gleak, cm_t, out);
}

// Round 6
// 108.711 us; speedup vs baseline: 1.3868x; 1.0319x over previous
//
#include <hip/hip_runtime.h>
#include <hip/hip_fp16.h>
#include <cstdint>

namespace {

typedef _Float16 h2 __attribute__((ext_vector_type(2)));

constexpr int BATCH   = 8192;
constexpr int IN      = 64;
constexpr int U       = 128;
constexpr int R       = 4;        // batches per thread
constexpr int TB      = 32;       // batches per block
constexpr int NT      = 1024;     // threads per block (16 waves)
constexpr int UNFOLDS = 3;
constexpr int PAD     = 36;       // floats per LDS row
constexpr float LOG2E = 1.4426950408889634f;

union HU { uint32_t u; h2 h; };

__device__ __forceinline__ uint32_t pack2(float lo, float hi) {
  __half l = __float2half_rn(lo);
  __half h = __float2half_rn(hi);
  return (uint32_t)__half_as_ushort(l) | ((uint32_t)__half_as_ushort(h) << 16);
}

// Gate pair with ONE rcp: sigma0 = a1*r, sigma1 = a0*r, r = rcp(a0*a1),
// a_k = 1 + 2^(A_k*v_k+B_k). Accumulate via packed f16 dot2.
__device__ __forceinline__ void gate2(float A0, float B0, float A1, float B1,
                                      h2 wpk, h2 wepk, float v0, float v1,
                                      float& num, float& den) {
  const float t0 = fmaf(A0, v0, B0);              // -log2e*sigma*(v-mu)
  const float t1 = fmaf(A1, v1, B1);
  const float e0 = __builtin_amdgcn_exp2f(t0);
  const float e1 = __builtin_amdgcn_exp2f(t1);
  const float a0 = 1.0f + e0;
  const float a1 = 1.0f + e1;
  const float r  = __builtin_amdgcn_rcpf(a0 * a1);
  const float rc0 = a1 * r;                       // sigmoid(x0)
  const float rc1 = a0 * r;                       // sigmoid(x1)
  const h2 rpk = __builtin_bit_cast(h2, __builtin_amdgcn_cvt_pkrtz(rc0, rc1));
  den = __builtin_amdgcn_fdot2(rpk, wpk,  den, false);  // += W0*rc0 + W1*rc1
  num = __builtin_amdgcn_fdot2(rpk, wepk, num, false);  // += We0*rc0 + We1*rc1
}

__global__ __launch_bounds__(NT, 4)
void ltc_fused(const float* __restrict__ inputs, const float* __restrict__ state,
               const float* __restrict__ s_mu, const float* __restrict__ s_sigma,
               const float* __restrict__ s_W, const float* __restrict__ s_erev,
               const float* __restrict__ r_mu, const float* __restrict__ r_sigma,
               const float* __restrict__ r_W, const float* __restrict__ r_erev,
               const float* __restrict__ vleak, const float* __restrict__ gleak,
               const float* __restrict__ cm_t, float* __restrict__ out)
{
  // 128 KB: recurrent i-pair packs {AB0, AB1, Wpk, Wepk}; sensory reuses 64 KB.
  __shared__ uint4 pack_s[(U / 2) * U];
  __shared__ float vp_s[U][PAD];        // v_pre, [presyn i][b_local]
  __shared__ float inp_s[IN][PAD];      // inputs, [i][b_local]

  const int tid = threadIdx.x;
  const int u   = tid & (U - 1);
  const int bl  = tid >> 7;             // 0..7
  const int b0  = blockIdx.x * TB;

  // per-u constants
  const float cm   = cm_t[u];
  const float gl   = gleak[u];
  const float numc = gl * vleak[u];
  const float denc = cm + gl + 1e-8f;

  // ---- stage sensory packs (i-pair interleaved) ----
  for (int k = tid; k < (IN / 2) * U; k += NT) {
    const int p  = k >> 7;              // pair index
    const int uu = k & (U - 1);
    const int i0 = 2 * p, i1 = i0 + 1;
    const float sg0 = s_sigma[i0 * U + uu], sg1 = s_sigma[i1 * U + uu];
    const float w0  = s_W[i0 * U + uu],     w1  = s_W[i1 * U + uu];
    uint4 q;
    q.x = pack2(-LOG2E * sg0, LOG2E * sg0 * s_mu[i0 * U + uu]);
    q.y = pack2(-LOG2E * sg1, LOG2E * sg1 * s_mu[i1 * U + uu]);
    q.z = pack2(w0, w1);
    q.w = pack2(w0 * s_erev[i0 * U + uu], w1 * s_erev[i1 * U + uu]);
    pack_s[k] = q;
  }
  // ---- stage inputs transposed: inp_s[i][b_local] ----
  for (int k = tid; k < TB * IN; k += NT) {
    const int bloc = k >> 6;
    const int i    = k & (IN - 1);
    inp_s[i][bloc] = inputs[b0 * IN + k];
  }
  // ---- stage state transposed: vp_s[i][b_local] ----
  for (int k = tid; k < TB * U; k += NT) {
    const int bloc = k >> 7;
    const int i    = k & (U - 1);
    vp_s[i][bloc] = state[b0 * U + k];
  }
  float vo[R];
#pragma unroll
  for (int r = 0; r < R; ++r) vo[r] = state[(b0 + bl * R + r) * U + u];
  __syncthreads();

  // ---- sensory reduction over IN (32 pairs) ----
  float num_s[R], den_s[R];
#pragma unroll
  for (int r = 0; r < R; ++r) { num_s[r] = 0.f; den_s[r] = 0.f; }
#pragma unroll 4
  for (int p = 0; p < IN / 2; ++p) {
    const uint4 q = pack_s[p * U + u];
    const float4 va = *reinterpret_cast<const float4*>(&inp_s[2 * p][bl * R]);
    const float4 vb = *reinterpret_cast<const float4*>(&inp_s[2 * p + 1][bl * R]);
    HU x, y, z, w; x.u = q.x; y.u = q.y; z.u = q.z; w.u = q.w;
    const float A0 = (float)x.h.x, B0 = (float)x.h.y;
    const float A1 = (float)y.h.x, B1 = (float)y.h.y;
#pragma unroll
    for (int r = 0; r < R; ++r)
      gate2(A0, B0, A1, B1, z.h, w.h, (&va.x)[r], (&vb.x)[r], num_s[r], den_s[r]);
  }
  __syncthreads();  // sensory region reads done

  // ---- stage recurrent packs (overwrites sensory region) ----
  for (int k = tid; k < (U / 2) * U; k += NT) {
    const int p  = k >> 7;
    const int uu = k & (U - 1);
    const int i0 = 2 * p, i1 = i0 + 1;
    const float sg0 = r_sigma[i0 * U + uu], sg1 = r_sigma[i1 * U + uu];
    const float w0  = r_W[i0 * U + uu],     w1  = r_W[i1 * U + uu];
    uint4 q;
    q.x = pack2(-LOG2E * sg0, LOG2E * sg0 * r_mu[i0 * U + uu]);
    q.y = pack2(-LOG2E * sg1, LOG2E * sg1 * r_mu[i1 * U + uu]);
    q.z = pack2(w0, w1);
    q.w = pack2(w0 * r_erev[i0 * U + uu], w1 * r_erev[i1 * U + uu]);
    pack_s[k] = q;
  }
  __syncthreads();

  // ---- 3 unfolds (64 pairs each) ----
#pragma unroll
  for (int t = 0; t < UNFOLDS; ++t) {
    float num[R], den[R];
#pragma unroll
    for (int r = 0; r < R; ++r) { num[r] = num_s[r]; den[r] = den_s[r]; }
#pragma unroll 4
    for (int p = 0; p < U / 2; ++p) {
      const uint4 q = pack_s[p * U + u];
      const float4 va = *reinterpret_cast<const float4*>(&vp_s[2 * p][bl * R]);
      const float4 vb = *reinterpret_cast<const float4*>(&vp_s[2 * p + 1][bl * R]);
      HU x, y, z, w; x.u = q.x; y.u = q.y; z.u = q.z; w.u = q.w;
      const float A0 = (float)x.h.x, B0 = (float)x.h.y;
      const float A1 = (float)y.h.x, B1 = (float)y.h.y;
#pragma unroll
      for (int r = 0; r < R; ++r)
        gate2(A0, B0, A1, B1, z.h, w.h, (&va.x)[r], (&vb.x)[r], num[r], den[r]);
    }
    float vnew[R];
#pragma unroll
    for (int r = 0; r < R; ++r) {
      vnew[r] = (fmaf(cm, vo[r], numc) + num[r]) * __builtin_amdgcn_rcpf(denc + den[r]);
      vo[r] = vnew[r];
    }
    if (t == UNFOLDS - 1) {
#pragma unroll
      for (int r = 0; r < R; ++r) out[(b0 + bl * R + r) * U + u] = vnew[r];
    } else {
      __syncthreads();  // all reads of vp_s done
      *reinterpret_cast<float4*>(&vp_s[u][bl * R]) =
          make_float4(vnew[0], vnew[1], vnew[2], vnew[3]);
      __syncthreads();
    }
  }
}

} // namespace

extern "C" void kernel_launch(void* const* d_in, const int* in_sizes, int n_in,
                              void* d_out, int out_size, void* d_ws, size_t ws_size,
                              hipStream_t stream) {
  const float* inputs   = (const float*)d_in[0];
  const float* state    = (const float*)d_in[1];
  const float* s_mu     = (const float*)d_in[2];
  const float* s_sigma  = (const float*)d_in[3];
  const float* s_W      = (const float*)d_in[4];
  const float* s_erev   = (const float*)d_in[5];
  const float* r_mu     = (const float*)d_in[6];
  const float* r_sigma  = (const float*)d_in[7];
  const float* r_W      = (const float*)d_in[8];
  const float* r_erev   = (const float*)d_in[9];
  const float* vleak    = (const float*)d_in[10];
  const float* gleak    = (const float*)d_in[11];
  const float* cm_t     = (const float*)d_in[12];
  float* out = (float*)d_out;

  ltc_fused<<<dim3(BATCH / TB), dim3(NT), 0, stream>>>(
      inputs, state, s_mu, s_sigma, s_W, s_erev,
      r_mu, r_sigma, r_W, r_erev, vleak, gleak, cm_t, out);
}